// Round 1
// baseline (323.192 us; speedup 1.0000x reference)
//
#include <hip/hip_runtime.h>

#define N 6144
#define IN_SZ 1024
#define CHUNK 64
#define NCH_REC (N / CHUNK)        // 96
#define NCH_IN (IN_SZ / CHUNK)     // 16
#define NCH (NCH_REC + NCH_IN)     // 112

// output layout (flat float32, return order)
#define OFF_SPK 0
#define OFF_ACT 6144
#define OFF_V 6154
#define OFF_MEM 12298
#define OFF_W 18442
#define OFF_HIST 37767178

// K1: sparse spike-driven matvec partials.
// grid (6, 112): x = 1024-col chunk (256 thr * float4), y = 64-row chunk.
// y < 96 -> W_rec rows with pre = hist[:,1]; y >= 96 -> W_in rows with input_spk.
// Unconditional partial write -> no ws zero-init needed.
__global__ __launch_bounds__(256) void k1_matvec(
    const float* __restrict__ Wrec, const float* __restrict__ Win,
    const float* __restrict__ hist, const float* __restrict__ inp,
    float* __restrict__ partial) {
  int by = blockIdx.y;
  bool isRec = by < NCH_REC;
  int rbase = isRec ? by * CHUNK : (by - NCH_REC) * CHUNK;
  const float* M = isRec ? Wrec : Win;
  __shared__ float sp[CHUNK];
  int tid = threadIdx.x;
  if (tid < CHUNK) sp[tid] = isRec ? hist[2 * (rbase + tid) + 1] : inp[rbase + tid];
  __syncthreads();
  int j0 = (blockIdx.x * 256 + tid) * 4;
  float4 acc = make_float4(0.f, 0.f, 0.f, 0.f);
  for (int r = 0; r < CHUNK; ++r) {
    if (sp[r] != 0.0f) {  // wave-uniform branch: skip HBM read of silent rows
      const float4 w = *(const float4*)(M + (size_t)(rbase + r) * N + j0);
      acc.x += w.x; acc.y += w.y; acc.z += w.z; acc.w += w.w;
    }
  }
  *(float4*)(partial + (size_t)by * N + j0) = acc;
}

// K2: neuron state update, 6144 threads.
__global__ __launch_bounds__(256) void k2_neuron(
    const float* __restrict__ partial, const float* __restrict__ V,
    const float* __restrict__ mem, const float* __restrict__ noise,
    const float* __restrict__ hist, float* __restrict__ out,
    float* __restrict__ ws_pre, float* __restrict__ ws_post) {
  int j = blockIdx.x * 256 + threadIdx.x;
  float cur = 0.f;
#pragma unroll 8
  for (int c = 0; c < NCH; ++c) cur += partial[c * N + j];
  const float decay = expf(-0.1f);
  float v = V[j] * decay + cur + 0.015f * noise[j];
  bool spk = v >= 1.0f;
  float s = spk ? 1.0f : 0.0f;
  float vn = spk ? 0.0f : v;
  out[OFF_SPK + j] = s;
  out[OFF_V + j] = vn;
  out[OFF_MEM + j] = 0.95f * mem[j] + 0.05f * s;  // 0.05f == f32(1.0-0.95)
  float pr = hist[2 * j + 1];
  out[OFF_HIST + 2 * j] = pr;      // shifted history slot 0 = old slot 1
  out[OFF_HIST + 2 * j + 1] = s;   // new slot 1 = current spikes
  ws_pre[j] = pr;
  ws_post[j] = s;
}

// K3: action_rates = spikes @ W_out, single block, full write (poisoned d_out).
__global__ __launch_bounds__(256) void k3_action(
    const float* __restrict__ ws_post, const float* __restrict__ Wout,
    float* __restrict__ out) {
  int tid = threadIdx.x;
  float acc[10];
#pragma unroll
  for (int k = 0; k < 10; ++k) acc[k] = 0.f;
  for (int s = 0; s < N / 256; ++s) {
    int i = s * 256 + tid;
    if (ws_post[i] != 0.f) {
#pragma unroll
      for (int k = 0; k < 10; ++k) acc[k] += Wout[i * 10 + k];
    }
  }
  __shared__ float red[4][10];
#pragma unroll
  for (int k = 0; k < 10; ++k) {
    float v = acc[k];
    for (int off = 32; off > 0; off >>= 1) v += __shfl_down(v, off, 64);
    if ((tid & 63) == 0) red[tid >> 6][k] = v;
  }
  __syncthreads();
  if (tid < 10)
    out[OFF_ACT + tid] = red[0][tid] + red[1][tid] + red[2][tid] + red[3][tid];
}

// K4: STDP + decay + clip over all of W_rec. 302 MB stream -> the dominant cost.
// grid (6, 6144): y = row i, x*256 threads * float4 = 6144 cols.
// Output offset 18442 is 8B-aligned only -> float2 stores.
__global__ __launch_bounds__(256) void k4_update(
    const float* __restrict__ Wrec, const float* __restrict__ ws_pre,
    const float* __restrict__ ws_post, float* __restrict__ out) {
  const float kp = 0.008f * expf(-1.0f / 16.8f);
  const float km = -0.0084f * expf(1.0f / 33.7f);
  const float wd = 0.9999999f;  // f32(1 - 1e-7)
  int i = blockIdx.y;
  int j0 = (blockIdx.x * 256 + threadIdx.x) * 4;
  float a = kp * ws_pre[i];   // coeff on post[j]
  float b = km * ws_post[i];  // coeff on pre[j]
  const float4 w = *(const float4*)(Wrec + (size_t)i * N + j0);
  float wv[4] = {w.x, w.y, w.z, w.w};
  float r[4];
  if (a != 0.f || b != 0.f) {  // wave-uniform; ~19% of rows
    const float4 po = *(const float4*)(ws_post + j0);
    const float4 pr = *(const float4*)(ws_pre + j0);
    float pov[4] = {po.x, po.y, po.z, po.w};
    float prv[4] = {pr.x, pr.y, pr.z, pr.w};
#pragma unroll
    for (int c = 0; c < 4; ++c) {
      float dw = (wv[c] != 0.f) ? (a * pov[c] + b * prv[c]) : 0.f;
      r[c] = fminf(fmaxf((wv[c] + dw) * wd, -1.5f), 1.5f);
    }
  } else {
#pragma unroll
    for (int c = 0; c < 4; ++c) r[c] = fminf(fmaxf(wv[c] * wd, -1.5f), 1.5f);
  }
  size_t base = (size_t)OFF_W + (size_t)i * N + j0;  // even
  float2* o2 = (float2*)out;
  o2[base / 2] = make_float2(r[0], r[1]);
  o2[base / 2 + 1] = make_float2(r[2], r[3]);
}

extern "C" void kernel_launch(void* const* d_in, const int* in_sizes, int n_in,
                              void* d_out, int out_size, void* d_ws,
                              size_t ws_size, hipStream_t stream) {
  const float* inp = (const float*)d_in[0];    // input_spk (1,1024)
  const float* V = (const float*)d_in[1];      // V (1,6144)
  const float* hist = (const float*)d_in[2];   // spike_history (1,6144,2)
  const float* mem = (const float*)d_in[3];    // mem (1,6144)
  const float* Wrec = (const float*)d_in[4];   // W_rec (6144,6144)
  const float* Win = (const float*)d_in[5];    // W_in (1024,6144)
  const float* Wout = (const float*)d_in[6];   // W_out (6144,10)
  const float* noise = (const float*)d_in[7];  // noise (1,6144)
  float* out = (float*)d_out;
  float* ws = (float*)d_ws;
  float* partial = ws;                      // 112*6144 floats
  float* ws_pre = ws + (size_t)NCH * N;     // 6144
  float* ws_post = ws_pre + N;              // 6144  (total ~2.8 MB)

  k1_matvec<<<dim3(6, NCH), 256, 0, stream>>>(Wrec, Win, hist, inp, partial);
  k2_neuron<<<dim3(24), 256, 0, stream>>>(partial, V, mem, noise, hist, out,
                                          ws_pre, ws_post);
  k3_action<<<dim3(1), 256, 0, stream>>>(ws_post, Wout, out);
  k4_update<<<dim3(6, N), 256, 0, stream>>>(Wrec, ws_pre, ws_post, out);
}

// Round 3
// 306.078 us; speedup vs baseline: 1.0559x; 1.0559x over previous
//
#include <hip/hip_runtime.h>

#define N 6144
#define IN_SZ 1024
#define CHUNK 64
#define NCH_REC (N / CHUNK)        // 96
#define NCH_IN (IN_SZ / CHUNK)     // 16
#define NCH (NCH_REC + NCH_IN)     // 112
#define NBLK2 24                   // K2 blocks (N/256)

typedef float v4f __attribute__((ext_vector_type(4)));
typedef float v2f __attribute__((ext_vector_type(2)));

// output layout (flat float32, return order)
#define OFF_SPK 0
#define OFF_ACT 6144
#define OFF_V 6154
#define OFF_MEM 12298
#define OFF_W 18442                // % 4 == 2 -> row stores are 8B-aligned
#define OFF_HIST 37767178

// K1: sparse spike-driven matvec partials.
// grid (6, 112): x = 1024-col chunk (256 thr * float4), y = 64-row chunk.
// y < 96 -> W_rec rows gated by pre = hist[:,1]; y >= 96 -> W_in gated by input_spk.
// Unconditional partial write -> no ws zero-init needed.
__global__ __launch_bounds__(256) void k1_matvec(
    const float* __restrict__ Wrec, const float* __restrict__ Win,
    const float* __restrict__ hist, const float* __restrict__ inp,
    float* __restrict__ partial) {
  int by = blockIdx.y;
  bool isRec = by < NCH_REC;
  int rbase = isRec ? by * CHUNK : (by - NCH_REC) * CHUNK;
  const float* M = isRec ? Wrec : Win;
  __shared__ float sp[CHUNK];
  int tid = threadIdx.x;
  if (tid < CHUNK) sp[tid] = isRec ? hist[2 * (rbase + tid) + 1] : inp[rbase + tid];
  __syncthreads();
  int j0 = (blockIdx.x * 256 + tid) * 4;
  float4 acc = make_float4(0.f, 0.f, 0.f, 0.f);
  for (int r = 0; r < CHUNK; ++r) {
    if (sp[r] != 0.0f) {  // block-uniform branch: skip HBM read of silent rows
      const float4 w = *(const float4*)(M + (size_t)(rbase + r) * N + j0);
      acc.x += w.x; acc.y += w.y; acc.z += w.z; acc.w += w.w;
    }
  }
  *(float4*)(partial + (size_t)by * N + j0) = acc;
}

// K2: neuron state update + per-block action_rate partials. 24 blocks x 256.
__global__ __launch_bounds__(256) void k2_neuron(
    const float* __restrict__ partial, const float* __restrict__ V,
    const float* __restrict__ mem, const float* __restrict__ noise,
    const float* __restrict__ hist, const float* __restrict__ Wout,
    float* __restrict__ out, float* __restrict__ ws_pre,
    float* __restrict__ ws_post, float* __restrict__ ws_act) {
  int tid = threadIdx.x;
  int j = blockIdx.x * 256 + tid;
  float cur = 0.f;
#pragma unroll 8
  for (int c = 0; c < NCH; ++c) cur += partial[c * N + j];
  const float decay = expf(-0.1f);
  float v = V[j] * decay + cur + 0.015f * noise[j];
  bool spk = v >= 1.0f;
  float s = spk ? 1.0f : 0.0f;
  out[OFF_SPK + j] = s;
  out[OFF_V + j] = spk ? 0.0f : v;
  out[OFF_MEM + j] = 0.95f * mem[j] + 0.05f * s;
  float pr = hist[2 * j + 1];
  out[OFF_HIST + 2 * j] = pr;      // shifted history slot 0 = old slot 1
  out[OFF_HIST + 2 * j + 1] = s;   // new slot 1 = current spikes
  ws_pre[j] = pr;
  ws_post[j] = s;

  // action partial: sum_j s_j * Wout[j][k] over this block's 256 neurons
  float acc[10];
#pragma unroll
  for (int k = 0; k < 10; ++k) acc[k] = 0.f;
  if (spk) {
#pragma unroll
    for (int k = 0; k < 10; ++k) acc[k] = Wout[j * 10 + k];
  }
  __shared__ float red[4][10];
#pragma unroll
  for (int k = 0; k < 10; ++k) {
    float x = acc[k];
    for (int off = 32; off > 0; off >>= 1) x += __shfl_down(x, off, 64);
    if ((tid & 63) == 0) red[tid >> 6][k] = x;
  }
  __syncthreads();
  if (tid < 10)
    ws_act[blockIdx.x * 10 + tid] =
        red[0][tid] + red[1][tid] + red[2][tid] + red[3][tid];
}

// K3: final action reduce. Full write of the 10 outputs (d_out is poisoned).
__global__ __launch_bounds__(64) void k3_action_final(
    const float* __restrict__ ws_act, float* __restrict__ out) {
  int k = threadIdx.x;
  if (k < 10) {
    float s = 0.f;
#pragma unroll
    for (int b = 0; b < NBLK2; ++b) s += ws_act[b * 10 + k];
    out[OFF_ACT + k] = s;
  }
}

// K4: STDP + decay + clip over all of W_rec — the 302 MB stream.
// One block per row (6144 blocks), 6 column-tiles of 1024 floats.
// Non-temporal loads/stores: pure streaming, keep it out of L2.
__global__ __launch_bounds__(256) void k4_update(
    const float* __restrict__ Wrec, const float* __restrict__ ws_pre,
    const float* __restrict__ ws_post, float* __restrict__ out) {
  const float kp = 0.008f * expf(-1.0f / 16.8f);
  const float km = -0.0084f * expf(1.0f / 33.7f);
  const float wd = 0.9999999f;  // f32(1 - 1e-7)
  int i = blockIdx.x;
  float a = kp * ws_pre[i];   // coeff on post[j]
  float b = km * ws_post[i];  // coeff on pre[j]
  const float* wrow = Wrec + (size_t)i * N;
  float* orow = out + (size_t)OFF_W + (size_t)i * N;  // 8B-aligned
  int t4 = threadIdx.x * 4;
  if (a != 0.f || b != 0.f) {  // block-uniform; ~19% of rows
#pragma unroll
    for (int tile = 0; tile < N; tile += 1024) {
      int j0 = tile + t4;
      v4f w = __builtin_nontemporal_load((const v4f*)(wrow + j0));
      v4f po = *(const v4f*)(ws_post + j0);  // reused across rows: cache
      v4f pr = *(const v4f*)(ws_pre + j0);
      float r[4];
#pragma unroll
      for (int c = 0; c < 4; ++c) {
        float dw = (w[c] != 0.f) ? (a * po[c] + b * pr[c]) : 0.f;
        r[c] = fminf(fmaxf((w[c] + dw) * wd, -1.5f), 1.5f);
      }
      v2f lo = {r[0], r[1]}, hi = {r[2], r[3]};
      __builtin_nontemporal_store(lo, (v2f*)(orow + j0));
      __builtin_nontemporal_store(hi, (v2f*)(orow + j0 + 2));
    }
  } else {
#pragma unroll
    for (int tile = 0; tile < N; tile += 1024) {
      int j0 = tile + t4;
      v4f w = __builtin_nontemporal_load((const v4f*)(wrow + j0));
      float r[4];
#pragma unroll
      for (int c = 0; c < 4; ++c)
        r[c] = fminf(fmaxf(w[c] * wd, -1.5f), 1.5f);
      v2f lo = {r[0], r[1]}, hi = {r[2], r[3]};
      __builtin_nontemporal_store(lo, (v2f*)(orow + j0));
      __builtin_nontemporal_store(hi, (v2f*)(orow + j0 + 2));
    }
  }
}

extern "C" void kernel_launch(void* const* d_in, const int* in_sizes, int n_in,
                              void* d_out, int out_size, void* d_ws,
                              size_t ws_size, hipStream_t stream) {
  const float* inp = (const float*)d_in[0];    // input_spk (1,1024)
  const float* V = (const float*)d_in[1];      // V (1,6144)
  const float* hist = (const float*)d_in[2];   // spike_history (1,6144,2)
  const float* mem = (const float*)d_in[3];    // mem (1,6144)
  const float* Wrec = (const float*)d_in[4];   // W_rec (6144,6144)
  const float* Win = (const float*)d_in[5];    // W_in (1024,6144)
  const float* Wout = (const float*)d_in[6];   // W_out (6144,10)
  const float* noise = (const float*)d_in[7];  // noise (1,6144)
  float* out = (float*)d_out;
  float* ws = (float*)d_ws;
  float* partial = ws;                      // 112*6144
  float* ws_pre = ws + (size_t)NCH * N;     // 6144
  float* ws_post = ws_pre + N;              // 6144
  float* ws_act = ws_post + N;              // 240

  k1_matvec<<<dim3(6, NCH), 256, 0, stream>>>(Wrec, Win, hist, inp, partial);
  k2_neuron<<<dim3(NBLK2), 256, 0, stream>>>(partial, V, mem, noise, hist, Wout,
                                             out, ws_pre, ws_post, ws_act);
  k3_action_final<<<dim3(1), 64, 0, stream>>>(ws_act, out);
  k4_update<<<dim3(N), 256, 0, stream>>>(Wrec, ws_pre, ws_post, out);
}